// Round 3
// baseline (312.982 us; speedup 1.0000x reference)
//
#include <hip/hip_runtime.h>
#include <math.h>

// Router: x[8192,4096] fp32; Wg,Wc[64,4096]; scores=|cls*silu(gate)|, softmax,
// top-8 of scores+bias, weights = 1 + scores*extra_scale (gathered).
// Out: weights [8192,8] fp32, then indices [8192,8] written as float values.
//
// v4: same 3-way bf16 split / 6-product MFMA math as v3 (bit-identical
// accumulation order -> same absmax-0 result), restructured for latency:
//  - wave = 32 rows x 64 cols (12 B-frag loads/iter instead of 24; grid 2x)
//  - explicit 1-iteration register software-pipeline (k-unroll 2, two named
//    A/B register sets): iteration i issues ALL of i+1's loads, then MFMAs.
// v3 was pure latency-bound: MfmaUtil 13.7, VALUBusy 9, HBM 9% -- 24 loads/iter
// serialized in small chunks at VGPR=80 with 2 waves/SIMD.

#define T_DIM 8192
#define D_DIM 4096
#define E_DIM 64
#define N2    128      // 64 gate cols + 64 cls cols
#define KTOP  8
#define MB_ROWS 64     // block tile rows (4 waves: 2 row-halves x 2 col-halves)

typedef __attribute__((ext_vector_type(8)))  short bfrag8;   // 8 bf16 (4 VGPRs)
typedef __attribute__((ext_vector_type(16))) float f32x16;   // 32x32 C/D frag

__device__ __forceinline__ unsigned short f2bf_rne(float f) {
    unsigned int u = __float_as_uint(f);
    unsigned int r = u + 0x7fffu + ((u >> 16) & 1u);        // round-nearest-even
    return (unsigned short)(r >> 16);
}
__device__ __forceinline__ float bf2f(unsigned short h) {
    return __uint_as_float(((unsigned int)h) << 16);
}
// v = bf2f(h) + bf2f(m) + bf2f(l) + eps, |eps| <= 2^-27 |v|
__device__ __forceinline__ void split3(float v, unsigned short& h,
                                       unsigned short& m, unsigned short& l) {
    h = f2bf_rne(v);
    const float r1 = v - bf2f(h);          // exact in fp32
    m = f2bf_rne(r1);
    const float r2 = r1 - bf2f(m);         // exact in fp32
    l = f2bf_rne(r2);
}

// ---------------- Kernel 0: W -> Whi + Wmid + Wlo (bf16), row-major [128][4096]
__global__ __launch_bounds__(256)
void router_prep(const float* __restrict__ Wg, const float* __restrict__ Wc,
                 unsigned short* __restrict__ Whi, unsigned short* __restrict__ Wmid,
                 unsigned short* __restrict__ Wlo)
{
    const int i   = blockIdx.x * 256 + threadIdx.x;  // float4 index, 131072 total
    const int row = i >> 10;                         // 1024 float4 per row
    const float* src = (row < E_DIM) ? (Wg + (size_t)row * D_DIM)
                                     : (Wc + (size_t)(row - E_DIM) * D_DIM);
    const float4 w = ((const float4*)src)[i & 1023];
    const float v[4] = {w.x, w.y, w.z, w.w};
    ushort4 hv, mv, lv;
    split3(v[0], hv.x, mv.x, lv.x);
    split3(v[1], hv.y, mv.y, lv.y);
    split3(v[2], hv.z, mv.z, lv.z);
    split3(v[3], hv.w, mv.w, lv.w);
    *(ushort4*)(Whi  + (size_t)i * 4) = hv;
    *(ushort4*)(Wmid + (size_t)i * 4) = mv;
    *(ushort4*)(Wlo  + (size_t)i * 4) = lv;
}

// ---------------- Kernel 1: 3-way-split MFMA GEMM, partials P[ks][T][128] ------
struct ASet { float4 c[4]; };                 // 16 fp32 of x (one 32-k step)
struct BSet { bfrag8 h[4], m[4], l[4]; };     // [n*2+h2] fragments

__device__ __forceinline__ void loadA(ASet& A, const float* __restrict__ xr, int kk, int lh)
{
    const float* p = xr + kk + lh * 8;
    A.c[0] = *(const float4*)(p);
    A.c[1] = *(const float4*)(p + 4);
    A.c[2] = *(const float4*)(p + 16);
    A.c[3] = *(const float4*)(p + 20);
}

__device__ __forceinline__ void loadB(BSet& B,
                                      const unsigned short* __restrict__ Whi,
                                      const unsigned short* __restrict__ Wmid,
                                      const unsigned short* __restrict__ Wlo,
                                      size_t base /* (nbase+l31)*D + kk + lh*8 */)
{
    #pragma unroll
    for (int n = 0; n < 2; ++n)
        #pragma unroll
        for (int h2 = 0; h2 < 2; ++h2) {
            const size_t off = base + (size_t)n * 32 * D_DIM + h2 * 16;
            B.h[n * 2 + h2] = *(const bfrag8*)(Whi  + off);
            B.m[n * 2 + h2] = *(const bfrag8*)(Wmid + off);
            B.l[n * 2 + h2] = *(const bfrag8*)(Wlo  + off);
        }
}

__device__ __forceinline__ void splitA(const ASet& A, bfrag8 ah[2], bfrag8 am[2], bfrag8 al[2])
{
    #pragma unroll
    for (int h2 = 0; h2 < 2; ++h2) {
        const float4 q0 = A.c[h2 * 2], q1 = A.c[h2 * 2 + 1];
        const float f[8] = {q0.x, q0.y, q0.z, q0.w, q1.x, q1.y, q1.z, q1.w};
        #pragma unroll
        for (int j = 0; j < 8; ++j) {
            unsigned short h, m, l;
            split3(f[j], h, m, l);
            ah[h2][j] = (short)h; am[h2][j] = (short)m; al[h2][j] = (short)l;
        }
    }
}

__device__ __forceinline__ void mfmaStep(f32x16 acc[2], const bfrag8 ah[2],
                                         const bfrag8 am[2], const bfrag8 al[2],
                                         const BSet& B)
{
    #pragma unroll
    for (int n = 0; n < 2; ++n)
        #pragma unroll
        for (int h2 = 0; h2 < 2; ++h2) {
            const int q = n * 2 + h2;
            // smallest products first (same order as v3 -> identical fp32 result)
            acc[n] = __builtin_amdgcn_mfma_f32_32x32x16_bf16(ah[h2], B.l[q], acc[n], 0, 0, 0);
            acc[n] = __builtin_amdgcn_mfma_f32_32x32x16_bf16(al[h2], B.h[q], acc[n], 0, 0, 0);
            acc[n] = __builtin_amdgcn_mfma_f32_32x32x16_bf16(am[h2], B.m[q], acc[n], 0, 0, 0);
            acc[n] = __builtin_amdgcn_mfma_f32_32x32x16_bf16(ah[h2], B.m[q], acc[n], 0, 0, 0);
            acc[n] = __builtin_amdgcn_mfma_f32_32x32x16_bf16(am[h2], B.h[q], acc[n], 0, 0, 0);
            acc[n] = __builtin_amdgcn_mfma_f32_32x32x16_bf16(ah[h2], B.h[q], acc[n], 0, 0, 0);
        }
}

// Block: 256 thr = 4 waves in 2x2: wr=wid>>1 row-half (32 rows), wc=wid&1 col-half
// (64 cols = 2 n-tiles). Grid: (128 M-blocks, S K-slices) = 1024 blocks.
// Per wave-iter: 12 B-frag loads + 4 A loads (all prefetched 1 iter ahead),
// 24 MFMAs. No LDS, no barriers.
__global__ __launch_bounds__(256, 2)
void router_gemm(const float* __restrict__ x,
                 const unsigned short* __restrict__ Whi,
                 const unsigned short* __restrict__ Wmid,
                 const unsigned short* __restrict__ Wlo,
                 float* __restrict__ P,
                 int sliceK)
{
    const int tid  = threadIdx.x;
    const int lane = tid & 63;
    const int wid  = tid >> 6;
    const int wr   = wid >> 1;
    const int wc   = wid & 1;
    const int l31  = lane & 31;
    const int lh   = lane >> 5;          // k-group (0/1)
    const int mb   = blockIdx.x;
    const int ks   = blockIdx.y;
    const int k0   = ks * sliceK;
    const int kend = k0 + sliceK;        // sliceK is a multiple of 64
    const int row0 = mb * MB_ROWS + wr * 32;
    const int nbase = wc * 64;

    f32x16 acc[2];
    #pragma unroll
    for (int n = 0; n < 2; ++n)
        #pragma unroll
        for (int r = 0; r < 16; ++r)
            acc[n][r] = 0.f;

    const float* xr = x + (size_t)(row0 + l31) * D_DIM;
    const size_t bbase = (size_t)(nbase + l31) * D_DIM + lh * 8;

    ASet aX, aY;
    BSet bX, bY;
    bfrag8 ah[2], am[2], al[2];

    loadA(aX, xr, k0, lh);
    loadB(bX, Whi, Wmid, Wlo, bbase + k0);

    for (int kk = k0; kk < kend; kk += 64) {
        // ---- step 0: consume (aX, bX) for k-step kk; prefetch kk+32
        splitA(aX, ah, am, al);
        if (kk + 32 < kend) {
            loadA(aY, xr, kk + 32, lh);
            loadB(bY, Whi, Wmid, Wlo, bbase + kk + 32);
        }
        mfmaStep(acc, ah, am, al, bX);

        // ---- step 1: consume (aY, bY) for k-step kk+32; prefetch kk+64
        splitA(aY, ah, am, al);
        if (kk + 64 < kend) {
            loadA(aX, xr, kk + 64, lh);
            loadB(bX, Whi, Wmid, Wlo, bbase + kk + 64);
        }
        mfmaStep(acc, ah, am, al, bY);
    }

    // store partial C tile: P[ks][row][col]
    // C/D (m74/m101): col = lane&31, row = (r&3) + 8*(r>>2) + 4*(lane>>5)
    float* Pb = P + ((size_t)ks * T_DIM + row0) * N2 + nbase + l31;
    #pragma unroll
    for (int n = 0; n < 2; ++n)
        #pragma unroll
        for (int r = 0; r < 16; ++r) {
            const int wrow = (r & 3) + 8 * (r >> 2) + 4 * lh;
            Pb[(size_t)wrow * N2 + n * 32] = acc[n][r];
        }
}

// ---------------- Kernel 2: reduce slices + silu/abs/softmax + biased top-8 ----
// (unchanged from the passing kernel — exact index ordering proven)
__global__ __launch_bounds__(256)
void router_topk(const float* __restrict__ P,
                 const float* __restrict__ scale,
                 const float* __restrict__ bias,
                 float* __restrict__ out,
                 int ksplit)
{
    const int lane = threadIdx.x & 63;   // expert id
    const int wid  = threadIdx.x >> 6;
    const int row  = blockIdx.x * 4 + wid;

    float g = 0.f, c = 0.f;
    for (int ks = 0; ks < ksplit; ++ks) {
        const float* p = P + ((size_t)ks * T_DIM + row) * N2;
        g += p[lane];
        c += p[E_DIM + lane];
    }
    const float sg = g / (1.f + expf(-g));   // silu(gate)
    const float v  = fabsf(c * sg);          // score pre-softmax

    // fp32 softmax across the 64 lanes
    float m = v;
    #pragma unroll
    for (int off = 32; off >= 1; off >>= 1) m = fmaxf(m, __shfl_xor(m, off));
    const float e = expf(v - m);
    float Z = e;
    #pragma unroll
    for (int off = 32; off >= 1; off >>= 1) Z += __shfl_xor(Z, off);
    const float s = e / Z;

    const float sc  = scale[lane];
    float cur = s + bias[lane];              // selection key

    float myw = 0.f; int myi = 0;
    #pragma unroll
    for (int j = 0; j < KTOP; ++j) {
        // wave argmax, ties -> lowest index (matches jax.lax.top_k)
        float bv = cur; int bi = lane;
        #pragma unroll
        for (int off = 32; off >= 1; off >>= 1) {
            const float ov = __shfl_xor(bv, off);
            const int   oi = __shfl_xor(bi, off);
            if (ov > bv || (ov == bv && oi < bi)) { bv = ov; bi = oi; }
        }
        const float s_bi  = __shfl(s,  bi);
        const float sc_bi = __shfl(sc, bi);
        const float w = 1.f + s_bi * sc_bi;  // "original" gathered at bi
        if (lane == j)  { myw = w; myi = bi; }
        if (lane == bi) cur = -INFINITY;
    }

    if (lane < KTOP) {
        out[(size_t)row * KTOP + lane] = myw;
        out[(size_t)T_DIM * KTOP + (size_t)row * KTOP + lane] = (float)myi;
    }
}

extern "C" void kernel_launch(void* const* d_in, const int* in_sizes, int n_in,
                              void* d_out, int out_size, void* d_ws, size_t ws_size,
                              hipStream_t stream)
{
    const float* x  = (const float*)d_in[0];
    const float* Wg = (const float*)d_in[1];
    const float* Wc = (const float*)d_in[2];
    const float* sc = (const float*)d_in[3];
    const float* bs = (const float*)d_in[4];
    float* out = (float*)d_out;
    float* P   = (float*)d_ws;

    const size_t PER = (size_t)T_DIM * N2 * sizeof(float);           // 4 MB per slice
    const size_t WSP = (size_t)N2 * D_DIM * sizeof(unsigned short);  // 1 MB per W part

    // Need S*4MB (partials) + 3MB (W split); degrade gracefully if ws is small.
    int S = 8;
    while (S > 1 && (size_t)S * PER + 3 * WSP > ws_size) S >>= 1;
    const int sliceK = D_DIM / S;

    unsigned short* Whi  = (unsigned short*)((char*)d_ws + (size_t)S * PER);
    unsigned short* Wmid = Whi + (size_t)N2 * D_DIM;
    unsigned short* Wlo  = Wmid + (size_t)N2 * D_DIM;

    router_prep<<<512, 256, 0, stream>>>(Wg, Wc, Whi, Wmid, Wlo);
    router_gemm<<<dim3(T_DIM / MB_ROWS, S), 256, 0, stream>>>(x, Whi, Wmid, Wlo, P, sliceK);
    router_topk<<<T_DIM / 4, 256, 0, stream>>>(P, sc, bs, out, S);
}

// Round 4
// 298.410 us; speedup vs baseline: 1.0488x; 1.0488x over previous
//
#include <hip/hip_runtime.h>
#include <math.h>

// Router: x[8192,4096] fp32; Wg,Wc[64,4096]; scores=|cls*silu(gate)|, softmax,
// top-8 of scores+bias, weights = 1 + scores*extra_scale (gathered).
// Out: weights [8192,8] fp32, then indices [8192,8] written as float values.
//
// v5: same 3-way bf16-split / 6-product MFMA math as v3 (bit-identical
// accumulation -> absmax 0), with the access patterns fixed:
//  - v3/v4 were latency-bound (MfmaUtil 13%) because A and B fragment loads
//    are 32-line GATHERS (lane stride = matrix row). Fix:
//  - B: W pre-packed into fragment-major layout (prep kernel) -> every B
//    fragment load is a wave-contiguous 1KB dwordx4 from L2-resident 3MB.
//  - A: staged via global_load_lds (async, coalesced) into double-buffered
//    LDS; per-lane gather via ds_read_b128 with XOR-swizzle (source-side
//    pre-swizzle, LDS dest linear -- m173/m201 pattern) -> no bank conflicts.
//  - 2-phase pipeline: STAGE(next); compute(cur); __syncthreads.

#define T_DIM 8192
#define D_DIM 4096
#define E_DIM 64
#define N2    128      // 64 gate cols + 64 cls cols
#define KTOP  8
#define MB_ROWS 128    // rows per workgroup (4 waves x 32 rows)

typedef __attribute__((ext_vector_type(8)))  short bfrag8;   // 8 bf16 (4 VGPRs)
typedef __attribute__((ext_vector_type(16))) float f32x16;   // 32x32 C/D frag

__device__ __forceinline__ unsigned short f2bf_rne(float f) {
    unsigned int u = __float_as_uint(f);
    unsigned int r = u + 0x7fffu + ((u >> 16) & 1u);        // round-nearest-even
    return (unsigned short)(r >> 16);
}
__device__ __forceinline__ float bf2f(unsigned short h) {
    return __uint_as_float(((unsigned int)h) << 16);
}
// v = bf2f(h) + bf2f(m) + bf2f(l) + eps, |eps| <= 2^-27 |v|
__device__ __forceinline__ void split3(float v, unsigned short& h,
                                       unsigned short& m, unsigned short& l) {
    h = f2bf_rne(v);
    const float r1 = v - bf2f(h);          // exact in fp32
    m = f2bf_rne(r1);
    const float r2 = r1 - bf2f(m);         // exact in fp32
    l = f2bf_rne(r2);
}

__device__ __forceinline__ void gload16(const void* g, void* l) {
    __builtin_amdgcn_global_load_lds(
        (const __attribute__((address_space(1))) void*)g,
        (__attribute__((address_space(3))) void*)l, 16, 0, 0);
}

// ---------------- Kernel 0: W -> packed fragment-major bf16 hi/mid/lo ----------
// Wpk element index: ((((k32*4 + n)*3 + p)*2 + h2)*64 + lane)*8 + j
//   holds part-p of W[col = n*32 + (lane&31)][k32*32 + h2*16 + (lane>>5)*8 + j]
// => a wave's B fragment load is 64 lanes x 16B CONTIGUOUS (1 KB). Total 3 MB.
__global__ __launch_bounds__(256)
void router_prep(const float* __restrict__ Wg, const float* __restrict__ Wc,
                 unsigned short* __restrict__ Wpk)
{
    const int t   = blockIdx.x * 256 + threadIdx.x;  // 65536 threads
    const int col = t >> 9;                          // 0..127
    const int ch  = t & 511;                         // 8-float chunk within row
    const int k   = ch << 3;

    const float* src = (col < E_DIM) ? (Wg + (size_t)col * D_DIM)
                                     : (Wc + (size_t)(col - E_DIM) * D_DIM);
    const float4 w0 = ((const float4*)(src + k))[0];
    const float4 w1 = ((const float4*)(src + k))[1];
    const float v[8] = {w0.x, w0.y, w0.z, w0.w, w1.x, w1.y, w1.z, w1.w};

    unsigned short hv[8], mv[8], lv[8];
    #pragma unroll
    for (int j = 0; j < 8; ++j) split3(v[j], hv[j], mv[j], lv[j]);

    const int k32 = k >> 5, h2 = (k >> 4) & 1, lh = (k >> 3) & 1;
    const int n = col >> 5, lane = lh * 32 + (col & 31);
    const size_t base = ((((size_t)k32 * 4 + n) * 3 + 0) * 2 + h2) * 512 + (size_t)lane * 8;
    // p stride = 2*512 = 1024 elements
    *(ushort4*)(Wpk + base)          = make_ushort4(hv[0], hv[1], hv[2], hv[3]);
    *(ushort4*)(Wpk + base + 4)      = make_ushort4(hv[4], hv[5], hv[6], hv[7]);
    *(ushort4*)(Wpk + base + 1024)   = make_ushort4(mv[0], mv[1], mv[2], mv[3]);
    *(ushort4*)(Wpk + base + 1028)   = make_ushort4(mv[4], mv[5], mv[6], mv[7]);
    *(ushort4*)(Wpk + base + 2048)   = make_ushort4(lv[0], lv[1], lv[2], lv[3]);
    *(ushort4*)(Wpk + base + 2052)   = make_ushort4(lv[4], lv[5], lv[6], lv[7]);
}

// ---------------- Kernel 1: 3-way-split MFMA GEMM, partials P[ks][T][128] ------
// Block: 256 thr = 4 waves; wave w = rows w*32..w*32+31, all 128 cols (v3 tile).
// A: LDS-staged 128x32 fp32 (16 KB), double-buffered, global_load_lds width 16,
//    source pre-swizzled (chunk ^= row&7) so swizzled ds_read is conflict-free.
// B: direct wave-contiguous loads from packed Wpk (L1/L2-hot, shared by waves).
__global__ __launch_bounds__(256, 2)
void router_gemm(const float* __restrict__ x,
                 const unsigned short* __restrict__ Wpk,
                 float* __restrict__ P,
                 int sliceK)
{
    __shared__ float sA[2][MB_ROWS * 32];            // [buf][row*32 + chunk*4+e]

    const int tid  = threadIdx.x;
    const int lane = tid & 63;
    const int wid  = tid >> 6;
    const int l31  = lane & 31;
    const int lh   = lane >> 5;          // k-half of fragment (0/1)
    const int mb   = blockIdx.x;
    const int ks   = blockIdx.y;
    const int k0   = ks * sliceK;
    const int NT   = sliceK >> 5;        // 32-k steps
    const int brow0 = mb * MB_ROWS;
    const int rl   = wid * 32 + l31;     // this lane's row within the tile
    const int sw   = l31 & 7;            // read-side swizzle key (row & 7)

    f32x16 acc[4];
    #pragma unroll
    for (int n = 0; n < 4; ++n)
        #pragma unroll
        for (int r = 0; r < 16; ++r)
            acc[n][r] = 0.f;

    // ---- staging: 4 issues of 256 lanes x 16B; LDS dest linear (chunk*16),
    // global source chunk pre-swizzled: LDS[row][c] = x[row][c ^ (row&7)]
    #define STAGE(bf_, kk_)                                                      \
        {                                                                        \
            _Pragma("unroll")                                                    \
            for (int i_ = 0; i_ < 4; ++i_) {                                     \
                const int chunk_ = i_ * 256 + tid;                               \
                const int row_   = chunk_ >> 3;                                  \
                const int csrc_  = (chunk_ & 7) ^ (row_ & 7);                    \
                const float* gp_ = x + (size_t)(brow0 + row_) * D_DIM            \
                                     + (kk_) + csrc_ * 4;                        \
                gload16(gp_, &sA[bf_][chunk_ * 4]);                              \
            }                                                                    \
        }

    STAGE(0, k0);
    __syncthreads();                      // drains vmcnt before first use

    for (int t = 0; t < NT; ++t) {
        const int kk = k0 + t * 32;
        const int bf = t & 1;

        if (t + 1 < NT) STAGE(bf ^ 1, kk + 32);   // async, lands by next barrier

        // ---- A fragments from LDS (+ 3-way split), both k-halves h2=0,1
        bfrag8 ah[2], am[2], al[2];
        #pragma unroll
        for (int h2 = 0; h2 < 2; ++h2) {
            const int c0 = h2 * 4 + lh * 2;
            const float4 q0 = *(const float4*)&sA[bf][rl * 32 + ((c0    ) ^ sw) * 4];
            const float4 q1 = *(const float4*)&sA[bf][rl * 32 + ((c0 + 1) ^ sw) * 4];
            const float f[8] = {q0.x, q0.y, q0.z, q0.w, q1.x, q1.y, q1.z, q1.w};
            #pragma unroll
            for (int j = 0; j < 8; ++j) {
                unsigned short h, m, l;
                split3(f[j], h, m, l);
                ah[h2][j] = (short)h; am[h2][j] = (short)m; al[h2][j] = (short)l;
            }
        }

        // ---- B fragments (packed, wave-contiguous) + MFMAs, v3 order
        const size_t k32 = (size_t)(kk >> 5);
        #pragma unroll
        for (int n = 0; n < 4; ++n) {
            #pragma unroll
            for (int h2 = 0; h2 < 2; ++h2) {
                const unsigned short* bb =
                    Wpk + ((((k32 * 4 + n) * 3 + 0) * 2 + h2) * 64 + lane) * 8;
                const bfrag8 bh = *(const bfrag8*)(bb);
                const bfrag8 bm = *(const bfrag8*)(bb + 1024);
                const bfrag8 bl = *(const bfrag8*)(bb + 2048);
                // smallest products first (same order as v3 -> identical bits)
                acc[n] = __builtin_amdgcn_mfma_f32_32x32x16_bf16(ah[h2], bl, acc[n], 0, 0, 0);
                acc[n] = __builtin_amdgcn_mfma_f32_32x32x16_bf16(al[h2], bh, acc[n], 0, 0, 0);
                acc[n] = __builtin_amdgcn_mfma_f32_32x32x16_bf16(am[h2], bm, acc[n], 0, 0, 0);
                acc[n] = __builtin_amdgcn_mfma_f32_32x32x16_bf16(ah[h2], bm, acc[n], 0, 0, 0);
                acc[n] = __builtin_amdgcn_mfma_f32_32x32x16_bf16(am[h2], bh, acc[n], 0, 0, 0);
                acc[n] = __builtin_amdgcn_mfma_f32_32x32x16_bf16(ah[h2], bh, acc[n], 0, 0, 0);
            }
        }

        __syncthreads();                  // also drains staging vmcnt (m97)
    }

    // store partial C tile: P[ks][row][col]
    // C/D (m74/m101): col = lane&31, row = (r&3) + 8*(r>>2) + 4*(lane>>5)
    float* Pb = P + ((size_t)ks * T_DIM + brow0 + wid * 32) * N2 + l31;
    #pragma unroll
    for (int n = 0; n < 4; ++n)
        #pragma unroll
        for (int r = 0; r < 16; ++r) {
            const int wrow = (r & 3) + 8 * (r >> 2) + 4 * lh;
            Pb[(size_t)wrow * N2 + n * 32] = acc[n][r];
        }
}

// ---------------- Kernel 2: reduce slices + silu/abs/softmax + biased top-8 ----
// (unchanged from the passing kernel — exact index ordering proven)
__global__ __launch_bounds__(256)
void router_topk(const float* __restrict__ P,
                 const float* __restrict__ scale,
                 const float* __restrict__ bias,
                 float* __restrict__ out,
                 int ksplit)
{
    const int lane = threadIdx.x & 63;   // expert id
    const int wid  = threadIdx.x >> 6;
    const int row  = blockIdx.x * 4 + wid;

    float g = 0.f, c = 0.f;
    for (int ks = 0; ks < ksplit; ++ks) {
        const float* p = P + ((size_t)ks * T_DIM + row) * N2;
        g += p[lane];
        c += p[E_DIM + lane];
    }
    const float sg = g / (1.f + expf(-g));   // silu(gate)
    const float v  = fabsf(c * sg);          // score pre-softmax

    // fp32 softmax across the 64 lanes
    float m = v;
    #pragma unroll
    for (int off = 32; off >= 1; off >>= 1) m = fmaxf(m, __shfl_xor(m, off));
    const float e = expf(v - m);
    float Z = e;
    #pragma unroll
    for (int off = 32; off >= 1; off >>= 1) Z += __shfl_xor(Z, off);
    const float s = e / Z;

    const float sc  = scale[lane];
    float cur = s + bias[lane];              // selection key

    float myw = 0.f; int myi = 0;
    #pragma unroll
    for (int j = 0; j < KTOP; ++j) {
        // wave argmax, ties -> lowest index (matches jax.lax.top_k)
        float bv = cur; int bi = lane;
        #pragma unroll
        for (int off = 32; off >= 1; off >>= 1) {
            const float ov = __shfl_xor(bv, off);
            const int   oi = __shfl_xor(bi, off);
            if (ov > bv || (ov == bv && oi < bi)) { bv = ov; bi = oi; }
        }
        const float s_bi  = __shfl(s,  bi);
        const float sc_bi = __shfl(sc, bi);
        const float w = 1.f + s_bi * sc_bi;  // "original" gathered at bi
        if (lane == j)  { myw = w; myi = bi; }
        if (lane == bi) cur = -INFINITY;
    }

    if (lane < KTOP) {
        out[(size_t)row * KTOP + lane] = myw;
        out[(size_t)T_DIM * KTOP + (size_t)row * KTOP + lane] = (float)myi;
    }
}

extern "C" void kernel_launch(void* const* d_in, const int* in_sizes, int n_in,
                              void* d_out, int out_size, void* d_ws, size_t ws_size,
                              hipStream_t stream)
{
    const float* x  = (const float*)d_in[0];
    const float* Wg = (const float*)d_in[1];
    const float* Wc = (const float*)d_in[2];
    const float* sc = (const float*)d_in[3];
    const float* bs = (const float*)d_in[4];
    float* out = (float*)d_out;
    float* P   = (float*)d_ws;

    const size_t PER = (size_t)T_DIM * N2 * sizeof(float);           // 4 MB per slice
    const size_t WSP = (size_t)N2 * D_DIM * sizeof(unsigned short);  // 1 MB per W part

    // Need S*4MB (partials) + 3MB (packed W); degrade gracefully if ws is small.
    int S = 8;
    while (S > 1 && (size_t)S * PER + 3 * WSP > ws_size) S >>= 1;
    const int sliceK = D_DIM / S;

    unsigned short* Wpk = (unsigned short*)((char*)d_ws + (size_t)S * PER);

    router_prep<<<256, 256, 0, stream>>>(Wg, Wc, Wpk);
    router_gemm<<<dim3(T_DIM / MB_ROWS, S), 256, 0, stream>>>(x, Wpk, P, sliceK);
    router_topk<<<T_DIM / 4, 256, 0, stream>>>(P, sc, bs, out, S);
}

// Round 5
// 278.257 us; speedup vs baseline: 1.1248x; 1.0724x over previous
//
#include <hip/hip_runtime.h>
#include <math.h>

// Router: x[8192,4096] fp32; Wg,Wc[64,4096]; scores=|cls*silu(gate)|, softmax,
// top-8 of scores+bias, weights = 1 + scores*extra_scale (gathered).
// Out: weights [8192,8] fp32, then indices [8192,8] written as float values.
//
// v6: identical math/bits to v5 (same 3-way bf16 split, same 6-product order,
// same k-order and k-slices -> P bit-identical -> absmax 0), restructured for
// OCCUPANCY: v3/v4/v5 all had grid = 512 blocks = 2 waves/SIMD -- every
// latency exposed (MfmaUtil ~14%, all pipes idle). Now:
//   block = 512 thr = 8 waves (2 row-groups x 4 col-quarters),
//   wave = 32 rows x 32 cols (1 acc, 6 B-frag loads, 12 MFMAs per k-step),
//   grid = (128 M-blocks, 8 k-slices) = 1024 blocks = 8192 waves = 8/SIMD.
// A: LDS-staged 64x32 fp32 double-buffered via global_load_lds (src-side
// XOR-swizzle, v5-verified). B: packed fragment-major Wpk (v5-verified).

#define T_DIM 8192
#define D_DIM 4096
#define E_DIM 64
#define N2    128      // 64 gate cols + 64 cls cols
#define KTOP  8
#define MB_ROWS 64     // rows per workgroup (2 row-groups of 32)

typedef __attribute__((ext_vector_type(8)))  short bfrag8;   // 8 bf16 (4 VGPRs)
typedef __attribute__((ext_vector_type(16))) float f32x16;   // 32x32 C/D frag

__device__ __forceinline__ unsigned short f2bf_rne(float f) {
    unsigned int u = __float_as_uint(f);
    unsigned int r = u + 0x7fffu + ((u >> 16) & 1u);        // round-nearest-even
    return (unsigned short)(r >> 16);
}
__device__ __forceinline__ float bf2f(unsigned short h) {
    return __uint_as_float(((unsigned int)h) << 16);
}
// v = bf2f(h) + bf2f(m) + bf2f(l) + eps, |eps| <= 2^-27 |v|
__device__ __forceinline__ void split3(float v, unsigned short& h,
                                       unsigned short& m, unsigned short& l) {
    h = f2bf_rne(v);
    const float r1 = v - bf2f(h);          // exact in fp32
    m = f2bf_rne(r1);
    const float r2 = r1 - bf2f(m);         // exact in fp32
    l = f2bf_rne(r2);
}

__device__ __forceinline__ void gload16(const void* g, void* l) {
    __builtin_amdgcn_global_load_lds(
        (const __attribute__((address_space(1))) void*)g,
        (__attribute__((address_space(3))) void*)l, 16, 0, 0);
}

// ---------------- Kernel 0: W -> packed fragment-major bf16 hi/mid/lo ----------
// Wpk element index: ((((k32*4 + n)*3 + p)*2 + h2)*64 + lane)*8 + j
//   holds part-p of W[col = n*32 + (lane&31)][k32*32 + h2*16 + (lane>>5)*8 + j]
// => a wave's B fragment load is 64 lanes x 16B CONTIGUOUS (1 KB). Total 3 MB.
__global__ __launch_bounds__(256)
void router_prep(const float* __restrict__ Wg, const float* __restrict__ Wc,
                 unsigned short* __restrict__ Wpk)
{
    const int t   = blockIdx.x * 256 + threadIdx.x;  // 65536 threads
    const int col = t >> 9;                          // 0..127
    const int ch  = t & 511;                         // 8-float chunk within row
    const int k   = ch << 3;

    const float* src = (col < E_DIM) ? (Wg + (size_t)col * D_DIM)
                                     : (Wc + (size_t)(col - E_DIM) * D_DIM);
    const float4 w0 = ((const float4*)(src + k))[0];
    const float4 w1 = ((const float4*)(src + k))[1];
    const float v[8] = {w0.x, w0.y, w0.z, w0.w, w1.x, w1.y, w1.z, w1.w};

    unsigned short hv[8], mv[8], lv[8];
    #pragma unroll
    for (int j = 0; j < 8; ++j) split3(v[j], hv[j], mv[j], lv[j]);

    const int k32 = k >> 5, h2 = (k >> 4) & 1, lh = (k >> 3) & 1;
    const int n = col >> 5, lane = lh * 32 + (col & 31);
    const size_t base = ((((size_t)k32 * 4 + n) * 3 + 0) * 2 + h2) * 512 + (size_t)lane * 8;
    // p stride = 2*512 = 1024 elements
    *(ushort4*)(Wpk + base)          = make_ushort4(hv[0], hv[1], hv[2], hv[3]);
    *(ushort4*)(Wpk + base + 4)      = make_ushort4(hv[4], hv[5], hv[6], hv[7]);
    *(ushort4*)(Wpk + base + 1024)   = make_ushort4(mv[0], mv[1], mv[2], mv[3]);
    *(ushort4*)(Wpk + base + 1028)   = make_ushort4(mv[4], mv[5], mv[6], mv[7]);
    *(ushort4*)(Wpk + base + 2048)   = make_ushort4(lv[0], lv[1], lv[2], lv[3]);
    *(ushort4*)(Wpk + base + 2052)   = make_ushort4(lv[4], lv[5], lv[6], lv[7]);
}

// ---------------- Kernel 1: 3-way-split MFMA GEMM, partials P[ks][T][128] ------
// Block: 512 thr = 8 waves; wave = rows (wid>>2)*32.., cols (wid&3)*32..
// A: LDS 64x32 fp32 (8 KB), double-buffered, global_load_lds width 16,
//    source pre-swizzled (chunk ^= row&7); swizzled ds_read conflict-light.
// B: direct wave-contiguous loads from packed Wpk (L1/L2-hot, shared).
__global__ __launch_bounds__(512, 4)
void router_gemm(const float* __restrict__ x,
                 const unsigned short* __restrict__ Wpk,
                 float* __restrict__ P,
                 int sliceK)
{
    __shared__ float sA[2][MB_ROWS * 32];            // [buf][row*32 + chunk*4+e]

    const int tid  = threadIdx.x;
    const int lane = tid & 63;
    const int wid  = tid >> 6;
    const int wr   = wid >> 2;           // row-group (0/1)
    const int wc   = wid & 3;            // col-quarter = B n-tile
    const int l31  = lane & 31;
    const int lh   = lane >> 5;          // k-half of fragment (0/1)
    const int mb   = blockIdx.x;
    const int ks   = blockIdx.y;
    const int k0   = ks * sliceK;
    const int NT   = sliceK >> 5;        // 32-k steps
    const int brow0 = mb * MB_ROWS;
    const int rl   = wr * 32 + l31;      // this lane's A row within the tile
    const int sw   = l31 & 7;            // read-side swizzle key (row & 7)

    f32x16 acc;
    #pragma unroll
    for (int r = 0; r < 16; ++r) acc[r] = 0.f;

    // staging: 512 lanes x 16B = 8 KB; LDS dest linear (chunk*16),
    // global source chunk pre-swizzled: LDS[row][c] = x[row][c ^ (row&7)]
    #define STAGE(bf_, kk_)                                                      \
        {                                                                        \
            const int chunk_ = tid;                                              \
            const int row_   = chunk_ >> 3;                                      \
            const int csrc_  = (chunk_ & 7) ^ (row_ & 7);                        \
            const float* gp_ = x + (size_t)(brow0 + row_) * D_DIM                \
                                 + (kk_) + csrc_ * 4;                            \
            gload16(gp_, &sA[bf_][chunk_ * 4]);                                  \
        }

    STAGE(0, k0);
    __syncthreads();                      // drains vmcnt before first use

    for (int t = 0; t < NT; ++t) {
        const int kk = k0 + t * 32;
        const int bf = t & 1;

        if (t + 1 < NT) STAGE(bf ^ 1, kk + 32);   // async, lands by next barrier

        // ---- A fragments from LDS (+ 3-way split), both k-halves h2=0,1
        bfrag8 ah[2], am[2], al[2];
        #pragma unroll
        for (int h2 = 0; h2 < 2; ++h2) {
            const int c0 = h2 * 4 + lh * 2;
            const float4 q0 = *(const float4*)&sA[bf][rl * 32 + ((c0    ) ^ sw) * 4];
            const float4 q1 = *(const float4*)&sA[bf][rl * 32 + ((c0 + 1) ^ sw) * 4];
            const float f[8] = {q0.x, q0.y, q0.z, q0.w, q1.x, q1.y, q1.z, q1.w};
            #pragma unroll
            for (int j = 0; j < 8; ++j) {
                unsigned short h, m, l;
                split3(f[j], h, m, l);
                ah[h2][j] = (short)h; am[h2][j] = (short)m; al[h2][j] = (short)l;
            }
        }

        // ---- B fragments (packed, wave-contiguous) + MFMAs, v3 order
        const size_t k32 = (size_t)(kk >> 5);
        #pragma unroll
        for (int h2 = 0; h2 < 2; ++h2) {
            const unsigned short* bb =
                Wpk + ((((k32 * 4 + wc) * 3 + 0) * 2 + h2) * 64 + lane) * 8;
            const bfrag8 bh = *(const bfrag8*)(bb);
            const bfrag8 bm = *(const bfrag8*)(bb + 1024);
            const bfrag8 bl = *(const bfrag8*)(bb + 2048);
            // smallest products first (same order as v3/v5 -> identical bits)
            acc = __builtin_amdgcn_mfma_f32_32x32x16_bf16(ah[h2], bl, acc, 0, 0, 0);
            acc = __builtin_amdgcn_mfma_f32_32x32x16_bf16(al[h2], bh, acc, 0, 0, 0);
            acc = __builtin_amdgcn_mfma_f32_32x32x16_bf16(am[h2], bm, acc, 0, 0, 0);
            acc = __builtin_amdgcn_mfma_f32_32x32x16_bf16(ah[h2], bm, acc, 0, 0, 0);
            acc = __builtin_amdgcn_mfma_f32_32x32x16_bf16(am[h2], bh, acc, 0, 0, 0);
            acc = __builtin_amdgcn_mfma_f32_32x32x16_bf16(ah[h2], bh, acc, 0, 0, 0);
        }

        __syncthreads();                  // also drains staging vmcnt
    }

    // store partial C tile: P[ks][row][col]
    // C/D (m74/m101): col = lane&31, row = (r&3) + 8*(r>>2) + 4*(lane>>5)
    float* Pb = P + ((size_t)ks * T_DIM + brow0 + wr * 32) * N2 + wc * 32 + l31;
    #pragma unroll
    for (int r = 0; r < 16; ++r) {
        const int wrow = (r & 3) + 8 * (r >> 2) + 4 * lh;
        Pb[(size_t)wrow * N2] = acc[r];
    }
    #undef STAGE
}

// ---------------- Kernel 2: reduce slices + silu/abs/softmax + biased top-8 ----
// (unchanged from the passing kernel — exact index ordering proven)
__global__ __launch_bounds__(256)
void router_topk(const float* __restrict__ P,
                 const float* __restrict__ scale,
                 const float* __restrict__ bias,
                 float* __restrict__ out,
                 int ksplit)
{
    const int lane = threadIdx.x & 63;   // expert id
    const int wid  = threadIdx.x >> 6;
    const int row  = blockIdx.x * 4 + wid;

    float g = 0.f, c = 0.f;
    for (int ks = 0; ks < ksplit; ++ks) {
        const float* p = P + ((size_t)ks * T_DIM + row) * N2;
        g += p[lane];
        c += p[E_DIM + lane];
    }
    const float sg = g / (1.f + expf(-g));   // silu(gate)
    const float v  = fabsf(c * sg);          // score pre-softmax

    // fp32 softmax across the 64 lanes
    float m = v;
    #pragma unroll
    for (int off = 32; off >= 1; off >>= 1) m = fmaxf(m, __shfl_xor(m, off));
    const float e = expf(v - m);
    float Z = e;
    #pragma unroll
    for (int off = 32; off >= 1; off >>= 1) Z += __shfl_xor(Z, off);
    const float s = e / Z;

    const float sc  = scale[lane];
    float cur = s + bias[lane];              // selection key

    float myw = 0.f; int myi = 0;
    #pragma unroll
    for (int j = 0; j < KTOP; ++j) {
        // wave argmax, ties -> lowest index (matches jax.lax.top_k)
        float bv = cur; int bi = lane;
        #pragma unroll
        for (int off = 32; off >= 1; off >>= 1) {
            const float ov = __shfl_xor(bv, off);
            const int   oi = __shfl_xor(bi, off);
            if (ov > bv || (ov == bv && oi < bi)) { bv = ov; bi = oi; }
        }
        const float s_bi  = __shfl(s,  bi);
        const float sc_bi = __shfl(sc, bi);
        const float w = 1.f + s_bi * sc_bi;  // "original" gathered at bi
        if (lane == j)  { myw = w; myi = bi; }
        if (lane == bi) cur = -INFINITY;
    }

    if (lane < KTOP) {
        out[(size_t)row * KTOP + lane] = myw;
        out[(size_t)T_DIM * KTOP + (size_t)row * KTOP + lane] = (float)myi;
    }
}

extern "C" void kernel_launch(void* const* d_in, const int* in_sizes, int n_in,
                              void* d_out, int out_size, void* d_ws, size_t ws_size,
                              hipStream_t stream)
{
    const float* x  = (const float*)d_in[0];
    const float* Wg = (const float*)d_in[1];
    const float* Wc = (const float*)d_in[2];
    const float* sc = (const float*)d_in[3];
    const float* bs = (const float*)d_in[4];
    float* out = (float*)d_out;
    float* P   = (float*)d_ws;

    const size_t PER = (size_t)T_DIM * N2 * sizeof(float);           // 4 MB per slice
    const size_t WSP = (size_t)N2 * D_DIM * sizeof(unsigned short);  // 1 MB per W part

    // Need S*4MB (partials) + 3MB (packed W); degrade gracefully if ws is small.
    int S = 8;
    while (S > 1 && (size_t)S * PER + 3 * WSP > ws_size) S >>= 1;
    const int sliceK = D_DIM / S;

    unsigned short* Wpk = (unsigned short*)((char*)d_ws + (size_t)S * PER);

    router_prep<<<256, 256, 0, stream>>>(Wg, Wc, Wpk);
    router_gemm<<<dim3(T_DIM / MB_ROWS, S), 512, 0, stream>>>(x, Wpk, P, sliceK);
    router_topk<<<T_DIM / 4, 256, 0, stream>>>(P, sc, bs, out, S);
}

// Round 6
// 265.690 us; speedup vs baseline: 1.1780x; 1.0473x over previous
//
#include <hip/hip_runtime.h>
#include <math.h>

// Router: x[8192,4096] fp32; Wg,Wc[64,4096]; scores=|cls*silu(gate)|, softmax,
// top-8 of scores+bias, weights = 1 + scores*extra_scale (gathered).
// Out: weights [8192,8] fp32, then indices [8192,8] written as float values.
//
// v7: same math/bits as v5/v6 (3-way bf16 split, 6-product order, same k-order
// -> P bit-identical -> absmax 0). Structural fix: v6 re-did the A split3 in
// EVERY wave (~800 VALU cyc/wave/step vs 96 MFMA cyc -> VALU+barrier bound).
// Now each x element is split ONCE per block:
//   - register-stage x (thread float4, coalesced), split3 in regs,
//   - ds_write bf16 hi/mid/lo directly in FRAGMENT layout [p][h2][lane][8],
//   - waves read A-frags with one linear conflict-free ds_read_b128 each,
//   - barrier drains nothing heavy (no global_load_lds; T14 write-late).
// Block 256 thr = 4 waves (one 32-row tile, 4 col-quarters), grid (256,8).

#define T_DIM 8192
#define D_DIM 4096
#define E_DIM 64
#define N2    128      // 64 gate cols + 64 cls cols
#define KTOP  8
#define MB_ROWS 32     // rows per workgroup

typedef __attribute__((ext_vector_type(8)))  short bfrag8;   // 8 bf16 (4 VGPRs)
typedef __attribute__((ext_vector_type(16))) float f32x16;   // 32x32 C/D frag

__device__ __forceinline__ unsigned short f2bf_rne(float f) {
    unsigned int u = __float_as_uint(f);
    unsigned int r = u + 0x7fffu + ((u >> 16) & 1u);        // round-nearest-even
    return (unsigned short)(r >> 16);
}
__device__ __forceinline__ float bf2f(unsigned short h) {
    return __uint_as_float(((unsigned int)h) << 16);
}
// v = bf2f(h) + bf2f(m) + bf2f(l) + eps, |eps| <= 2^-27 |v|
__device__ __forceinline__ void split3(float v, unsigned short& h,
                                       unsigned short& m, unsigned short& l) {
    h = f2bf_rne(v);
    const float r1 = v - bf2f(h);          // exact in fp32
    m = f2bf_rne(r1);
    const float r2 = r1 - bf2f(m);         // exact in fp32
    l = f2bf_rne(r2);
}

// ---------------- Kernel 0: W -> packed fragment-major bf16 hi/mid/lo ----------
// Wpk element index: ((((k32*4 + n)*3 + p)*2 + h2)*64 + lane)*8 + j
//   holds part-p of W[col = n*32 + (lane&31)][k32*32 + h2*16 + (lane>>5)*8 + j]
// => a wave's B fragment load is 64 lanes x 16B CONTIGUOUS (1 KB). Total 3 MB.
__global__ __launch_bounds__(256)
void router_prep(const float* __restrict__ Wg, const float* __restrict__ Wc,
                 unsigned short* __restrict__ Wpk)
{
    const int t   = blockIdx.x * 256 + threadIdx.x;  // 65536 threads
    const int col = t >> 9;                          // 0..127
    const int ch  = t & 511;                         // 8-float chunk within row
    const int k   = ch << 3;

    const float* src = (col < E_DIM) ? (Wg + (size_t)col * D_DIM)
                                     : (Wc + (size_t)(col - E_DIM) * D_DIM);
    const float4 w0 = ((const float4*)(src + k))[0];
    const float4 w1 = ((const float4*)(src + k))[1];
    const float v[8] = {w0.x, w0.y, w0.z, w0.w, w1.x, w1.y, w1.z, w1.w};

    unsigned short hv[8], mv[8], lv[8];
    #pragma unroll
    for (int j = 0; j < 8; ++j) split3(v[j], hv[j], mv[j], lv[j]);

    const int k32 = k >> 5, h2 = (k >> 4) & 1, lh = (k >> 3) & 1;
    const int n = col >> 5, lane = lh * 32 + (col & 31);
    const size_t base = ((((size_t)k32 * 4 + n) * 3 + 0) * 2 + h2) * 512 + (size_t)lane * 8;
    // p stride = 2*512 = 1024 elements
    *(ushort4*)(Wpk + base)          = make_ushort4(hv[0], hv[1], hv[2], hv[3]);
    *(ushort4*)(Wpk + base + 4)      = make_ushort4(hv[4], hv[5], hv[6], hv[7]);
    *(ushort4*)(Wpk + base + 1024)   = make_ushort4(mv[0], mv[1], mv[2], mv[3]);
    *(ushort4*)(Wpk + base + 1028)   = make_ushort4(mv[4], mv[5], mv[6], mv[7]);
    *(ushort4*)(Wpk + base + 2048)   = make_ushort4(lv[0], lv[1], lv[2], lv[3]);
    *(ushort4*)(Wpk + base + 2052)   = make_ushort4(lv[4], lv[5], lv[6], lv[7]);
}

// ---------------- Kernel 1: 3-way-split MFMA GEMM, partials P[ks][T][128] ------
// Block: 256 thr = 4 waves; wave wc owns cols wc*32..wc*32+31, rows shared.
// sF layout: [buf][part][h2][le][8] where le = (k8&1)*32 + row; a wave's A-frag
// read at lane l is the 16B at [p][h2][l][0] -> 64 lanes x 16B linear (no
// conflicts). Staging thread (row=tid>>3, kq=tid&7) loads x float4 (coalesced),
// split3 once, writes 3x ushort4.
__global__ __launch_bounds__(256, 4)
void router_gemm(const float* __restrict__ x,
                 const unsigned short* __restrict__ Wpk,
                 float* __restrict__ P,
                 int sliceK)
{
    __shared__ unsigned short sF[2][3][2][64][8];    // 12 KB

    const int tid  = threadIdx.x;
    const int lane = tid & 63;
    const int wc   = tid >> 6;           // wave = col-quarter (B n-tile)
    const int l31  = lane & 31;
    const int lh   = lane >> 5;
    const int mb   = blockIdx.x;
    const int ks   = blockIdx.y;
    const int k0   = ks * sliceK;
    const int NT   = sliceK >> 5;        // 32-k steps
    const int brow0 = mb * MB_ROWS;

    // staging map: thread -> (row, kq) ; its float4 covers k_local kq*4..kq*4+3
    const int srow = tid >> 3;           // 0..31
    const int kq   = tid & 7;            // float4 chunk within 32-k step
    const int h2w  = kq >> 2;            // k8>>1
    const int lew  = ((kq >> 1) & 1) * 32 + srow;
    const int jw   = (kq & 1) * 4;
    const float* gsrc = x + (size_t)(brow0 + srow) * D_DIM + kq * 4;

    f32x16 acc;
    #pragma unroll
    for (int r = 0; r < 16; ++r) acc[r] = 0.f;

    #define WRITE_TILE(v_, bf_)                                                  \
        {                                                                        \
            ushort4 hv_, mv_, lv_;                                               \
            unsigned short h_, m_, l_;                                           \
            split3((v_).x, h_, m_, l_); hv_.x = h_; mv_.x = m_; lv_.x = l_;      \
            split3((v_).y, h_, m_, l_); hv_.y = h_; mv_.y = m_; lv_.y = l_;      \
            split3((v_).z, h_, m_, l_); hv_.z = h_; mv_.z = m_; lv_.z = l_;      \
            split3((v_).w, h_, m_, l_); hv_.w = h_; mv_.w = m_; lv_.w = l_;      \
            *(ushort4*)&sF[bf_][0][h2w][lew][jw] = hv_;                          \
            *(ushort4*)&sF[bf_][1][h2w][lew][jw] = mv_;                          \
            *(ushort4*)&sF[bf_][2][h2w][lew][jw] = lv_;                          \
        }

    {
        const float4 v0 = *(const float4*)(gsrc + k0);
        WRITE_TILE(v0, 0);
    }
    __syncthreads();

    for (int t = 0; t < NT; ++t) {
        const int bf = t & 1;
        const bool more = (t + 1 < NT);

        // issue next tile's global load EARLY (regs; waitcnt lands at WRITE_TILE)
        float4 nx;
        if (more) nx = *(const float4*)(gsrc + k0 + (t + 1) * 32);

        // A fragments: one linear conflict-free ds_read_b128 per (part, h2)
        bfrag8 ah[2], am[2], al[2];
        #pragma unroll
        for (int h2 = 0; h2 < 2; ++h2) {
            ah[h2] = *(const bfrag8*)&sF[bf][0][h2][lane][0];
            am[h2] = *(const bfrag8*)&sF[bf][1][h2][lane][0];
            al[h2] = *(const bfrag8*)&sF[bf][2][h2][lane][0];
        }

        // B fragments (packed, wave-contiguous) + MFMAs, v3/v5/v6 order
        const size_t k32 = (size_t)((k0 + t * 32) >> 5);
        #pragma unroll
        for (int h2 = 0; h2 < 2; ++h2) {
            const unsigned short* bb =
                Wpk + ((((k32 * 4 + wc) * 3 + 0) * 2 + h2) * 64 + lane) * 8;
            const bfrag8 bh = *(const bfrag8*)(bb);
            const bfrag8 bm = *(const bfrag8*)(bb + 1024);
            const bfrag8 bl = *(const bfrag8*)(bb + 2048);
            // smallest products first (same order as v3/v5/v6 -> identical bits)
            acc = __builtin_amdgcn_mfma_f32_32x32x16_bf16(ah[h2], bl, acc, 0, 0, 0);
            acc = __builtin_amdgcn_mfma_f32_32x32x16_bf16(al[h2], bh, acc, 0, 0, 0);
            acc = __builtin_amdgcn_mfma_f32_32x32x16_bf16(am[h2], bm, acc, 0, 0, 0);
            acc = __builtin_amdgcn_mfma_f32_32x32x16_bf16(ah[h2], bm, acc, 0, 0, 0);
            acc = __builtin_amdgcn_mfma_f32_32x32x16_bf16(am[h2], bh, acc, 0, 0, 0);
            acc = __builtin_amdgcn_mfma_f32_32x32x16_bf16(ah[h2], bh, acc, 0, 0, 0);
        }

        // write next tile into the other buffer (T14 write-late), then barrier
        if (more) WRITE_TILE(nx, bf ^ 1);
        __syncthreads();
    }
    #undef WRITE_TILE

    // store partial C tile: P[ks][row][col]
    // C/D (m74/m101): col = lane&31, row = (r&3) + 8*(r>>2) + 4*(lane>>5)
    float* Pb = P + ((size_t)ks * T_DIM + brow0) * N2 + wc * 32 + l31;
    #pragma unroll
    for (int r = 0; r < 16; ++r) {
        const int wrow = (r & 3) + 8 * (r >> 2) + 4 * lh;
        Pb[(size_t)wrow * N2] = acc[r];
    }
}

// ---------------- Kernel 2: reduce slices + silu/abs/softmax + biased top-8 ----
// (unchanged from the passing kernel — exact index ordering proven)
__global__ __launch_bounds__(256)
void router_topk(const float* __restrict__ P,
                 const float* __restrict__ scale,
                 const float* __restrict__ bias,
                 float* __restrict__ out,
                 int ksplit)
{
    const int lane = threadIdx.x & 63;   // expert id
    const int wid  = threadIdx.x >> 6;
    const int row  = blockIdx.x * 4 + wid;

    float g = 0.f, c = 0.f;
    for (int ks = 0; ks < ksplit; ++ks) {
        const float* p = P + ((size_t)ks * T_DIM + row) * N2;
        g += p[lane];
        c += p[E_DIM + lane];
    }
    const float sg = g / (1.f + expf(-g));   // silu(gate)
    const float v  = fabsf(c * sg);          // score pre-softmax

    // fp32 softmax across the 64 lanes
    float m = v;
    #pragma unroll
    for (int off = 32; off >= 1; off >>= 1) m = fmaxf(m, __shfl_xor(m, off));
    const float e = expf(v - m);
    float Z = e;
    #pragma unroll
    for (int off = 32; off >= 1; off >>= 1) Z += __shfl_xor(Z, off);
    const float s = e / Z;

    const float sc  = scale[lane];
    float cur = s + bias[lane];              // selection key

    float myw = 0.f; int myi = 0;
    #pragma unroll
    for (int j = 0; j < KTOP; ++j) {
        // wave argmax, ties -> lowest index (matches jax.lax.top_k)
        float bv = cur; int bi = lane;
        #pragma unroll
        for (int off = 32; off >= 1; off >>= 1) {
            const float ov = __shfl_xor(bv, off);
            const int   oi = __shfl_xor(bi, off);
            if (ov > bv || (ov == bv && oi < bi)) { bv = ov; bi = oi; }
        }
        const float s_bi  = __shfl(s,  bi);
        const float sc_bi = __shfl(sc, bi);
        const float w = 1.f + s_bi * sc_bi;  // "original" gathered at bi
        if (lane == j)  { myw = w; myi = bi; }
        if (lane == bi) cur = -INFINITY;
    }

    if (lane < KTOP) {
        out[(size_t)row * KTOP + lane] = myw;
        out[(size_t)T_DIM * KTOP + (size_t)row * KTOP + lane] = (float)myi;
    }
}

extern "C" void kernel_launch(void* const* d_in, const int* in_sizes, int n_in,
                              void* d_out, int out_size, void* d_ws, size_t ws_size,
                              hipStream_t stream)
{
    const float* x  = (const float*)d_in[0];
    const float* Wg = (const float*)d_in[1];
    const float* Wc = (const float*)d_in[2];
    const float* sc = (const float*)d_in[3];
    const float* bs = (const float*)d_in[4];
    float* out = (float*)d_out;
    float* P   = (float*)d_ws;

    const size_t PER = (size_t)T_DIM * N2 * sizeof(float);           // 4 MB per slice
    const size_t WSP = (size_t)N2 * D_DIM * sizeof(unsigned short);  // 1 MB per W part

    // Need S*4MB (partials) + 3MB (packed W); degrade gracefully if ws is small.
    int S = 8;
    while (S > 1 && (size_t)S * PER + 3 * WSP > ws_size) S >>= 1;
    const int sliceK = D_DIM / S;

    unsigned short* Wpk = (unsigned short*)((char*)d_ws + (size_t)S * PER);

    router_prep<<<256, 256, 0, stream>>>(Wg, Wc, Wpk);
    router_gemm<<<dim3(T_DIM / MB_ROWS, S), 256, 0, stream>>>(x, Wpk, P, sliceK);
    router_topk<<<T_DIM / 4, 256, 0, stream>>>(P, sc, bs, out, S);
}

// Round 8
// 249.035 us; speedup vs baseline: 1.2568x; 1.0669x over previous
//
#include <hip/hip_runtime.h>
#include <math.h>

// Router: x[8192,4096] fp32; Wg,Wc[64,4096]; scores=|cls*silu(gate)|, softmax,
// top-8 of scores+bias, weights = 1 + scores*extra_scale (gathered).
// Out: weights [8192,8] fp32, then indices [8192,8] written as float values.
//
// v8b: v8 with the compile fix (nontemporal builtins need clang ext_vector
// types, not HIP_vector_type float4). Math/bits identical to v5/v6/v7
// (3-way bf16 split, 6-product order, same per-acc k-order -> absmax 0).
//  - x loads & P stores NON-TEMPORAL (keep Wpk L2-resident; B = L2 hits)
//  - raw s_barrier + lgkmcnt(0) only (no per-iter vmcnt drain; m97 stall)
//  - wave tile 64x32 (2 acc chains, 24 MFMA/iter; half B traffic per FLOP)
//  - LDS part-stride padded (1040) to kill ds_write self-conflicts

#define T_DIM 8192
#define D_DIM 4096
#define E_DIM 64
#define N2    128      // 64 gate cols + 64 cls cols
#define KTOP  8
#define MB_ROWS 64     // rows per workgroup (wave = all 64 rows x 32 cols)

// LDS fragment layout strides (ushorts): [bf][rg][p][h2][le][j]
#define LDS_H2S 512
#define LDS_PS  1040   // 1024 + 16 pad -> parts shifted 8 banks
#define LDS_RGS (3 * LDS_PS)
#define LDS_BFS (2 * LDS_RGS)

typedef __attribute__((ext_vector_type(8)))  short bfrag8;   // 8 bf16 (4 VGPRs)
typedef __attribute__((ext_vector_type(16))) float f32x16;   // 32x32 C/D frag
typedef __attribute__((ext_vector_type(4)))  float f4;       // clang vec (nt ok)

__device__ __forceinline__ unsigned short f2bf_rne(float f) {
    unsigned int u = __float_as_uint(f);
    unsigned int r = u + 0x7fffu + ((u >> 16) & 1u);        // round-nearest-even
    return (unsigned short)(r >> 16);
}
__device__ __forceinline__ float bf2f(unsigned short h) {
    return __uint_as_float(((unsigned int)h) << 16);
}
// v = bf2f(h) + bf2f(m) + bf2f(l) + eps, |eps| <= 2^-27 |v|
__device__ __forceinline__ void split3(float v, unsigned short& h,
                                       unsigned short& m, unsigned short& l) {
    h = f2bf_rne(v);
    const float r1 = v - bf2f(h);          // exact in fp32
    m = f2bf_rne(r1);
    const float r2 = r1 - bf2f(m);         // exact in fp32
    l = f2bf_rne(r2);
}

// ---------------- Kernel 0: W -> packed fragment-major bf16 hi/mid/lo ----------
// Wpk element index: ((((k32*4 + n)*3 + p)*2 + h2)*64 + lane)*8 + j
//   holds part-p of W[col = n*32 + (lane&31)][k32*32 + h2*16 + (lane>>5)*8 + j]
// => a wave's B fragment load is 64 lanes x 16B CONTIGUOUS (1 KB). Total 3 MB.
__global__ __launch_bounds__(256)
void router_prep(const float* __restrict__ Wg, const float* __restrict__ Wc,
                 unsigned short* __restrict__ Wpk)
{
    const int t   = blockIdx.x * 256 + threadIdx.x;  // 65536 threads
    const int col = t >> 9;                          // 0..127
    const int ch  = t & 511;                         // 8-float chunk within row
    const int k   = ch << 3;

    const float* src = (col < E_DIM) ? (Wg + (size_t)col * D_DIM)
                                     : (Wc + (size_t)(col - E_DIM) * D_DIM);
    const float4 w0 = ((const float4*)(src + k))[0];
    const float4 w1 = ((const float4*)(src + k))[1];
    const float v[8] = {w0.x, w0.y, w0.z, w0.w, w1.x, w1.y, w1.z, w1.w};

    unsigned short hv[8], mv[8], lv[8];
    #pragma unroll
    for (int j = 0; j < 8; ++j) split3(v[j], hv[j], mv[j], lv[j]);

    const int k32 = k >> 5, h2 = (k >> 4) & 1, lh = (k >> 3) & 1;
    const int n = col >> 5, lane = lh * 32 + (col & 31);
    const size_t base = ((((size_t)k32 * 4 + n) * 3 + 0) * 2 + h2) * 512 + (size_t)lane * 8;
    // p stride = 2*512 = 1024 elements
    *(ushort4*)(Wpk + base)          = make_ushort4(hv[0], hv[1], hv[2], hv[3]);
    *(ushort4*)(Wpk + base + 4)      = make_ushort4(hv[4], hv[5], hv[6], hv[7]);
    *(ushort4*)(Wpk + base + 1024)   = make_ushort4(mv[0], mv[1], mv[2], mv[3]);
    *(ushort4*)(Wpk + base + 1028)   = make_ushort4(mv[4], mv[5], mv[6], mv[7]);
    *(ushort4*)(Wpk + base + 2048)   = make_ushort4(lv[0], lv[1], lv[2], lv[3]);
    *(ushort4*)(Wpk + base + 2052)   = make_ushort4(lv[4], lv[5], lv[6], lv[7]);
}

// ---------------- Kernel 1: 3-way-split MFMA GEMM, partials P[ks][T][128] ------
// Block: 256 thr = 4 waves; wave wc owns cols wc*32..wc*32+31 and ALL 64 rows
// (two 32-row groups -> acc[2]). Staging thread (srow=tid>>3, kq=tid&7) loads
// rows srow and srow+32 (nt f4), split3 once, ds_writes fragment layout.
__global__ __launch_bounds__(256, 4)
void router_gemm(const float* __restrict__ x,
                 const unsigned short* __restrict__ Wpk,
                 float* __restrict__ P,
                 int sliceK)
{
    __shared__ unsigned short sF[2 * LDS_BFS];       // ~24.4 KB

    const int tid  = threadIdx.x;
    const int lane = tid & 63;
    const int wc   = tid >> 6;           // wave = col-quarter (B n-tile)
    const int l31  = lane & 31;
    const int lh   = lane >> 5;
    const int mb   = blockIdx.x;
    const int ks   = blockIdx.y;
    const int k0   = ks * sliceK;
    const int NT   = sliceK >> 5;        // 32-k steps
    const int brow0 = mb * MB_ROWS;

    // staging map: thread -> (srow, kq); covers rows srow and srow+32
    const int srow = tid >> 3;           // 0..31
    const int kq   = tid & 7;            // float4 chunk within 32-k step
    const int h2w  = kq >> 2;
    const int lew  = ((kq >> 1) & 1) * 32 + srow;
    const int jw   = (kq & 1) * 4;
    const int wbase = h2w * LDS_H2S + lew * 8 + jw;  // + bf*BFS + rg*RGS + p*PS
    const float* gsrc0 = x + (size_t)(brow0 + srow) * D_DIM + k0 + kq * 4;
    const float* gsrc1 = gsrc0 + (size_t)32 * D_DIM;

    f32x16 acc[2];
    #pragma unroll
    for (int rg = 0; rg < 2; ++rg)
        #pragma unroll
        for (int r = 0; r < 16; ++r) acc[rg][r] = 0.f;

    // split one f4 into LDS at (bf, rg)
    #define WRITE_HALF(v_, bf_, rg_)                                             \
        {                                                                        \
            ushort4 hv_, mv_, lv_;                                               \
            unsigned short h_, m_, l_;                                           \
            split3((v_).x, h_, m_, l_); hv_.x = h_; mv_.x = m_; lv_.x = l_;      \
            split3((v_).y, h_, m_, l_); hv_.y = h_; mv_.y = m_; lv_.y = l_;      \
            split3((v_).z, h_, m_, l_); hv_.z = h_; mv_.z = m_; lv_.z = l_;      \
            split3((v_).w, h_, m_, l_); hv_.w = h_; mv_.w = m_; lv_.w = l_;      \
            const int o_ = (bf_) * LDS_BFS + (rg_) * LDS_RGS + wbase;            \
            *(ushort4*)&sF[o_]              = hv_;                               \
            *(ushort4*)&sF[o_ + LDS_PS]     = mv_;                               \
            *(ushort4*)&sF[o_ + 2 * LDS_PS] = lv_;                               \
        }

    // prologue: stage tile 0, start prefetch of tile 1
    {
        const f4 v0 = __builtin_nontemporal_load((const f4*)gsrc0);
        const f4 v1 = __builtin_nontemporal_load((const f4*)gsrc1);
        WRITE_HALF(v0, 0, 0);
        WRITE_HALF(v1, 0, 1);
    }
    f4 xa0 = {0,0,0,0}, xa1 = {0,0,0,0};   // data for tile t+1
    f4 xb0 = {0,0,0,0}, xb1 = {0,0,0,0};   // data for tile t+2
    if (NT > 1) {
        xa0 = __builtin_nontemporal_load((const f4*)(gsrc0 + 32));
        xa1 = __builtin_nontemporal_load((const f4*)(gsrc1 + 32));
    }
    asm volatile("s_waitcnt lgkmcnt(0)" ::: "memory");
    __builtin_amdgcn_s_barrier();

    for (int t = 0; t < NT; ++t) {
        const int bf = t & 1;
        const int fbase = bf * LDS_BFS;

        // issue depth-2 x prefetch (in flight across the barrier; nt)
        if (t + 2 < NT) {
            xb0 = __builtin_nontemporal_load((const f4*)(gsrc0 + (t + 2) * 32));
            xb1 = __builtin_nontemporal_load((const f4*)(gsrc1 + (t + 2) * 32));
        }

        // B (shared by both row-groups) + A frags + MFMAs; per-acc order = v7
        const size_t k32 = (size_t)((k0 + t * 32) >> 5);
        #pragma unroll
        for (int h2 = 0; h2 < 2; ++h2) {
            const unsigned short* bb =
                Wpk + ((((k32 * 4 + wc) * 3 + 0) * 2 + h2) * 64 + lane) * 8;
            const bfrag8 bh = *(const bfrag8*)(bb);
            const bfrag8 bm = *(const bfrag8*)(bb + 1024);
            const bfrag8 bl = *(const bfrag8*)(bb + 2048);
            #pragma unroll
            for (int rg = 0; rg < 2; ++rg) {
                const int ab = fbase + rg * LDS_RGS + h2 * LDS_H2S + lane * 8;
                const bfrag8 ah = *(const bfrag8*)&sF[ab];
                const bfrag8 am = *(const bfrag8*)&sF[ab + LDS_PS];
                const bfrag8 al = *(const bfrag8*)&sF[ab + 2 * LDS_PS];
                // smallest products first (same per-acc order as v3..v7)
                acc[rg] = __builtin_amdgcn_mfma_f32_32x32x16_bf16(ah, bl, acc[rg], 0, 0, 0);
                acc[rg] = __builtin_amdgcn_mfma_f32_32x32x16_bf16(al, bh, acc[rg], 0, 0, 0);
                acc[rg] = __builtin_amdgcn_mfma_f32_32x32x16_bf16(am, bm, acc[rg], 0, 0, 0);
                acc[rg] = __builtin_amdgcn_mfma_f32_32x32x16_bf16(ah, bm, acc[rg], 0, 0, 0);
                acc[rg] = __builtin_amdgcn_mfma_f32_32x32x16_bf16(am, bh, acc[rg], 0, 0, 0);
                acc[rg] = __builtin_amdgcn_mfma_f32_32x32x16_bf16(ah, bh, acc[rg], 0, 0, 0);
            }
        }

        // write tile t+1 into the other buffer (compiler waits vmcnt for xa)
        if (t + 1 < NT) {
            WRITE_HALF(xa0, bf ^ 1, 0);
            WRITE_HALF(xa1, bf ^ 1, 1);
        }
        // barrier: LDS visibility only -- vmcnt (x prefetch) stays in flight
        asm volatile("s_waitcnt lgkmcnt(0)" ::: "memory");
        __builtin_amdgcn_s_barrier();
        xa0 = xb0; xa1 = xb1;
    }
    #undef WRITE_HALF

    // store partial C tile: P[ks][row][col], non-temporal (read once by topk)
    // C/D (m74/m101): col = lane&31, row = (r&3) + 8*(r>>2) + 4*(lane>>5)
    #pragma unroll
    for (int rg = 0; rg < 2; ++rg) {
        float* Pb = P + ((size_t)ks * T_DIM + brow0 + rg * 32) * N2 + wc * 32 + l31;
        #pragma unroll
        for (int r = 0; r < 16; ++r) {
            const int wrow = (r & 3) + 8 * (r >> 2) + 4 * lh;
            __builtin_nontemporal_store(acc[rg][r], &Pb[(size_t)wrow * N2]);
        }
    }
}

// ---------------- Kernel 2: reduce slices + silu/abs/softmax + biased top-8 ----
// (unchanged from the passing kernel — exact index ordering proven)
__global__ __launch_bounds__(256)
void router_topk(const float* __restrict__ P,
                 const float* __restrict__ scale,
                 const float* __restrict__ bias,
                 float* __restrict__ out,
                 int ksplit)
{
    const int lane = threadIdx.x & 63;   // expert id
    const int wid  = threadIdx.x >> 6;
    const int row  = blockIdx.x * 4 + wid;

    float g = 0.f, c = 0.f;
    for (int ks = 0; ks < ksplit; ++ks) {
        const float* p = P + ((size_t)ks * T_DIM + row) * N2;
        g += p[lane];
        c += p[E_DIM + lane];
    }
    const float sg = g / (1.f + expf(-g));   // silu(gate)
    const float v  = fabsf(c * sg);          // score pre-softmax

    // fp32 softmax across the 64 lanes
    float m = v;
    #pragma unroll
    for (int off = 32; off >= 1; off >>= 1) m = fmaxf(m, __shfl_xor(m, off));
    const float e = expf(v - m);
    float Z = e;
    #pragma unroll
    for (int off = 32; off >= 1; off >>= 1) Z += __shfl_xor(Z, off);
    const float s = e / Z;

    const float sc  = scale[lane];
    float cur = s + bias[lane];              // selection key

    float myw = 0.f; int myi = 0;
    #pragma unroll
    for (int j = 0; j < KTOP; ++j) {
        // wave argmax, ties -> lowest index (matches jax.lax.top_k)
        float bv = cur; int bi = lane;
        #pragma unroll
        for (int off = 32; off >= 1; off >>= 1) {
            const float ov = __shfl_xor(bv, off);
            const int   oi = __shfl_xor(bi, off);
            if (ov > bv || (ov == bv && oi < bi)) { bv = ov; bi = oi; }
        }
        const float s_bi  = __shfl(s,  bi);
        const float sc_bi = __shfl(sc, bi);
        const float w = 1.f + s_bi * sc_bi;  // "original" gathered at bi
        if (lane == j)  { myw = w; myi = bi; }
        if (lane == bi) cur = -INFINITY;
    }

    if (lane < KTOP) {
        out[(size_t)row * KTOP + lane] = myw;
        out[(size_t)T_DIM * KTOP + (size_t)row * KTOP + lane] = (float)myi;
    }
}

extern "C" void kernel_launch(void* const* d_in, const int* in_sizes, int n_in,
                              void* d_out, int out_size, void* d_ws, size_t ws_size,
                              hipStream_t stream)
{
    const float* x  = (const float*)d_in[0];
    const float* Wg = (const float*)d_in[1];
    const float* Wc = (const float*)d_in[2];
    const float* sc = (const float*)d_in[3];
    const float* bs = (const float*)d_in[4];
    float* out = (float*)d_out;
    float* P   = (float*)d_ws;

    const size_t PER = (size_t)T_DIM * N2 * sizeof(float);           // 4 MB per slice
    const size_t WSP = (size_t)N2 * D_DIM * sizeof(unsigned short);  // 1 MB per W part

    // Need S*4MB (partials) + 3MB (packed W); degrade gracefully if ws is small.
    int S = 8;
    while (S > 1 && (size_t)S * PER + 3 * WSP > ws_size) S >>= 1;
    const int sliceK = D_DIM / S;

    unsigned short* Wpk = (unsigned short*)((char*)d_ws + (size_t)S * PER);

    router_prep<<<256, 256, 0, stream>>>(Wg, Wc, Wpk);
    router_gemm<<<dim3(T_DIM / MB_ROWS, S), 256, 0, stream>>>(x, Wpk, P, sliceK);
    router_topk<<<T_DIM / 4, 256, 0, stream>>>(P, sc, bs, out, S);
}